// Round 1
// 795.411 us; speedup vs baseline: 1.0399x; 1.0399x over previous
//
#include <hip/hip_runtime.h>

#define TT 4096      // tokens
#define DM 1024      // d_model
#define DF 4096      // d_ff
#define NE 8         // experts
#define NSLOT 8320   // 2*TT + 128 slack (partial-tile overreach)

typedef short bf16x8 __attribute__((ext_vector_type(8)));
typedef float f32x4  __attribute__((ext_vector_type(4)));

// ---------- ws layout (bytes), total ~209.4 MiB (requires ws_size >= 219,545,600) ----------
// ctrl block
#define CNT_OFF    0
#define OFFS_OFF   256
#define POS_OFF    512
#define METAI_OFF  4096                       // int[TT]
#define METAG_OFF  (METAI_OFF + 4*TT)         // float[TT]
#define TSLOT_OFF  (METAG_OFF + 4*TT)         // int[TT]  (s0 | s1<<16)
// big buffers
#define XG_OFF     131072                     // ushort[NSLOT*DM]      (dead after gemm1)
#define W1T_OFF    (XG_OFF + 2*NSLOT*DM)      // ushort[NE*DF*DM] bf16 [e][f][k]  (dead after gemm1)
#define H_OFF      (W1T_OFF + 2*NE*DM*DF)     // ushort[NSLOT*DF]
#define W2T_OFF    (H_OFF + 2*NSLOT*DF)       // ushort[NE*DM*DF] bf16 [e][d][k]
#define Y_OFF      XG_OFF                     // float[2][NSLOT*DM] aliases Xg+W1t (68.2MB <= 84.1MB)

// fp32 pair -> packed bf16x2 (RNE): low16 = bf16(a), high16 = bf16(b)
__device__ __forceinline__ unsigned pkbf(float a, float b) {
    unsigned ua = __float_as_uint(a), ub = __float_as_uint(b);
    ua += 0x7fffu + ((ua >> 16) & 1u);
    ub += 0x7fffu + ((ub >> 16) & 1u);
    return __builtin_amdgcn_perm(ub, ua, 0x07060302u);
}

// async global->LDS, 16B per lane. LDS dest is wave-uniform base + lane*16 (linear).
__device__ __forceinline__ void gll16(const void* g, void* l) {
    __builtin_amdgcn_global_load_lds(
        (const __attribute__((address_space(1))) void*)g,
        (__attribute__((address_space(3))) void*)l, 16, 0, 0);
}

// ---------------- init: zero cnt ----------------
__global__ void init_kernel(int* __restrict__ cnt)
{
    if (threadIdx.x < NE) cnt[threadIdx.x] = 0;
}

// ---------------- Router: 1 wave/token, fp32 exact (unchanged) ----------------
__global__ __launch_bounds__(256)
void router_kernel(const float* __restrict__ x, const float* __restrict__ Wr,
                   const float* __restrict__ br,
                   int* __restrict__ cnt, int* __restrict__ meta_i,
                   float* __restrict__ meta_g)
{
    const int t    = (blockIdx.x * blockDim.x + threadIdx.x) >> 6;
    const int lane = threadIdx.x & 63;
    if (t >= TT) return;
    const float* xr = x + (size_t)t * DM;

    float acc[NE];
#pragma unroll
    for (int e = 0; e < NE; e++) acc[e] = 0.f;
    for (int i = 0; i < DM / 64; i++) {
        int d = lane + (i << 6);
        float xv = xr[d];
        const float4* wr = (const float4*)(Wr + (size_t)d * NE);
        float4 w0 = wr[0], w1 = wr[1];
        acc[0] += xv * w0.x; acc[1] += xv * w0.y;
        acc[2] += xv * w0.z; acc[3] += xv * w0.w;
        acc[4] += xv * w1.x; acc[5] += xv * w1.y;
        acc[6] += xv * w1.z; acc[7] += xv * w1.w;
    }
#pragma unroll
    for (int e = 0; e < NE; e++)
#pragma unroll
        for (int off = 32; off > 0; off >>= 1)
            acc[e] += __shfl_down(acc[e], off, 64);

    if (lane == 0) {
        float lg[NE];
#pragma unroll
        for (int e = 0; e < NE; e++) lg[e] = acc[e] + br[e];
        int i0 = 0;
        for (int e = 1; e < NE; e++) if (lg[e] > lg[i0]) i0 = e;
        int i1 = (i0 == 0) ? 1 : 0;
        for (int e = 0; e < NE; e++) if (e != i0 && lg[e] > lg[i1]) i1 = e;
        float g0 = 1.f / (1.f + expf(lg[i1] - lg[i0]));  // renormalized top-2 softmax
        atomicAdd(&cnt[i0], 1);
        atomicAdd(&cnt[i1], 1);
        meta_i[t] = i0 | (i1 << 8);
        meta_g[t] = g0;
    }
}

// ---------------- scan: exclusive prefix over 8 counts ----------------
__global__ void scan_kernel(const int* __restrict__ cnt, int* __restrict__ offs,
                            int* __restrict__ pos)
{
    if (threadIdx.x == 0) {
        int o = 0;
        for (int e = 0; e < NE; e++) { offs[e] = o; pos[e] = o; o += cnt[e]; }
    }
}

// ---------------- scatter: slot assign + gather x -> bf16 Xg + token->slot map ----------------
__global__ __launch_bounds__(256)
void scatter_kernel(const float* __restrict__ x, const int* __restrict__ meta_i,
                    int* __restrict__ pos, int* __restrict__ tslot,
                    ushort* __restrict__ Xg)
{
    const int t    = (blockIdx.x * blockDim.x + threadIdx.x) >> 6;
    const int lane = threadIdx.x & 63;
    if (t >= TT) return;
    int s0 = 0, s1 = 0;
    if (lane == 0) {
        int mi = meta_i[t];
        int i0 = mi & 0xff, i1 = (mi >> 8) & 0xff;
        s0 = atomicAdd(&pos[i0], 1);
        s1 = atomicAdd(&pos[i1], 1);
        tslot[t] = s0 | (s1 << 16);
    }
    s0 = __shfl(s0, 0, 64);
    s1 = __shfl(s1, 0, 64);
    const float4* xr = (const float4*)(x + (size_t)t * DM);
#pragma unroll
    for (int i = 0; i < 4; i++) {
        float4 v = xr[lane + 64 * i];
        uint2 pv = make_uint2(pkbf(v.x, v.y), pkbf(v.z, v.w));
        *(uint2*)(Xg + (size_t)s0 * DM + (lane + 64 * i) * 4) = pv;
        *(uint2*)(Xg + (size_t)s1 * DM + (lane + 64 * i) * 4) = pv;
    }
}

// ---------------- wconv: W[e][K][F] fp32 -> Wt[e][F][K] bf16 (64x64 LDS tile transpose) ----------------
__global__ __launch_bounds__(256)
void wconv_kernel(const float* __restrict__ W, ushort* __restrict__ Wt, int K, int F)
{
    const int e  = blockIdx.z;
    const int k0 = blockIdx.y * 64, f0 = blockIdx.x * 64;
    const float* We = W + (size_t)e * K * F;
    ushort* Oe = Wt + (size_t)e * K * F;

    __shared__ char lds[64 * 136];   // [f][16 k-slots of 8B], row stride 136B

    const int tid = threadIdx.x;
    const int a = tid & 15, b = tid >> 4;    // a: f-group(4), b: k-group(4)

    const float* src = We + (size_t)(k0 + b * 4) * F + f0 + a * 4;
    float4 v0 = *(const float4*)(src);
    float4 v1 = *(const float4*)(src + F);
    float4 v2 = *(const float4*)(src + 2 * F);
    float4 v3 = *(const float4*)(src + 3 * F);
    const float* p0 = (const float*)&v0; const float* p1 = (const float*)&v1;
    const float* p2 = (const float*)&v2; const float* p3 = (const float*)&v3;
#pragma unroll
    for (int j = 0; j < 4; j++) {
        int f = a * 4 + j;
        uint2 pv = make_uint2(pkbf(p0[j], p1[j]), pkbf(p2[j], p3[j]));  // 4 consecutive k
        *(uint2*)(lds + f * 136 + ((b ^ a) * 8)) = pv;   // phys slot = logical ^ (f>>2)
    }
    __syncthreads();
#pragma unroll
    for (int i = 0; i < 2; i++) {
        int idx = tid + 256 * i;
        int fl = idx >> 3, kc = idx & 7;
        int xw = fl >> 2;
        uint2 lo = *(const uint2*)(lds + fl * 136 + (((kc * 2)     ^ xw) * 8));
        uint2 hi = *(const uint2*)(lds + fl * 136 + (((kc * 2 + 1) ^ xw) * 8));
        uint4 o = make_uint4(lo.x, lo.y, hi.x, hi.y);    // 8 consecutive k bf16
        *(uint4*)(Oe + (size_t)(f0 + fl) * K + k0 + kc * 8) = o;
    }
}

// ---------------- GEMM1: H = relu(Xg @ W1t^T + b1), bf16 out (m97 structure) ----------------
__global__ __launch_bounds__(256)
void gemm1_kernel(const ushort* __restrict__ Xg, const ushort* __restrict__ W1t,
                  const float* __restrict__ b1, const int* __restrict__ cnt,
                  const int* __restrict__ offs, ushort* __restrict__ H)
{
    const int e = blockIdx.z;
    const int n_e = cnt[e];
    const int t0 = blockIdx.y * 128;
    if (t0 >= n_e) return;
    const int ft0 = blockIdx.x * 128;
    const int slot0 = offs[e] + t0;
    const ushort* Be = W1t + (size_t)e * DF * DM;   // [f][k]

    __shared__ char smem[33792];   // As 16K | Bs 16K ; epilogue: Cb 64x132 f32

    const int tid = threadIdx.x;
    const int l = tid & 63, wid = tid >> 6;
    const int wm = (wid >> 1) * 64, wn = (wid & 1) * 64;
    const int lm = l & 15, q = l >> 4;

    f32x4 acc[4][4];
#pragma unroll
    for (int i = 0; i < 4; i++)
#pragma unroll
        for (int j = 0; j < 4; j++) acc[i][j] = (f32x4){0.f, 0.f, 0.f, 0.f};

    for (int k0 = 0; k0 < DM; k0 += 64) {
        __syncthreads();
        // A: linear LDS dest, inverse-swizzled global source (read key = row&7)
#pragma unroll
        for (int i = 0; i < 4; i++) {
            int cid = i * 256 + tid;
            int row = cid >> 3, p = cid & 7;
            int c = p ^ (row & 7);
            gll16(Xg + (size_t)(slot0 + row) * DM + k0 + c * 8, smem + cid * 16);
        }
        // B: same scheme, key = n&7
#pragma unroll
        for (int i = 0; i < 4; i++) {
            int cid = i * 256 + tid;
            int n = cid >> 3, p = cid & 7;
            int c = p ^ (n & 7);
            gll16(Be + (size_t)(ft0 + n) * DM + k0 + c * 8, smem + 16384 + cid * 16);
        }
        __syncthreads();
#pragma unroll
        for (int s = 0; s < 2; s++) {
            bf16x8 af[4], bfr[4];
#pragma unroll
            for (int i = 0; i < 4; i++) {
                int row = wm + i * 16 + lm;
                af[i] = *(const bf16x8*)(smem + row * 128 + ((((s << 2) + q) ^ (row & 7)) * 16));
            }
#pragma unroll
            for (int j = 0; j < 4; j++) {
                int n = wn + j * 16 + lm;
                bfr[j] = *(const bf16x8*)(smem + 16384 + n * 128 + ((((s << 2) + q) ^ (n & 7)) * 16));
            }
#pragma unroll
            for (int i = 0; i < 4; i++)
#pragma unroll
                for (int j = 0; j < 4; j++)
                    acc[i][j] = __builtin_amdgcn_mfma_f32_16x16x32_bf16(af[i], bfr[j], acc[i][j], 0, 0, 0);
        }
    }

    // epilogue: relu(+b1) -> bf16 H, LDS bounce per 64-row half
    float b1v[4];
#pragma unroll
    for (int j = 0; j < 4; j++) b1v[j] = b1[e * DF + ft0 + wn + j * 16 + lm];

    float* Cb = (float*)smem;   // [64][132]
    __syncthreads();
#pragma unroll
    for (int h = 0; h < 2; h++) {
        if ((wid >> 1) == h) {
#pragma unroll
            for (int i = 0; i < 4; i++)
#pragma unroll
                for (int j = 0; j < 4; j++)
#pragma unroll
                    for (int r = 0; r < 4; r++) {
                        int lrow = i * 16 + q * 4 + r;
                        int col = wn + j * 16 + lm;
                        Cb[lrow * 132 + col] = fmaxf(acc[i][j][r] + b1v[j], 0.f);
                    }
        }
        __syncthreads();
        {
            int row = tid >> 2, seg = tid & 3;
            // GUARD: partial tiles must not write H rows of the next expert's slots
            if (t0 + h * 64 + row < n_e) {
                size_t hbase = (size_t)(slot0 + h * 64 + row) * DF + ft0 + seg * 32;
#pragma unroll
                for (int i = 0; i < 4; i++) {
                    float4 a = *(const float4*)&Cb[row * 132 + seg * 32 + i * 8];
                    float4 b = *(const float4*)&Cb[row * 132 + seg * 32 + i * 8 + 4];
                    uint4 o;
                    o.x = pkbf(a.x, a.y); o.y = pkbf(a.z, a.w);
                    o.z = pkbf(b.x, b.y); o.w = pkbf(b.z, b.w);
                    *(uint4*)(H + hbase + i * 8) = o;
                }
            }
        }
        __syncthreads();
    }
}

// ---------------- GEMM2: Y[kz] = H @ W2t^T (+b2 on kz=0), plain fp32 stores ----------------
__global__ __launch_bounds__(256)
void gemm2_kernel(const ushort* __restrict__ H, const ushort* __restrict__ W2t,
                  const float* __restrict__ b2, const int* __restrict__ cnt,
                  const int* __restrict__ offs, float* __restrict__ Y)
{
    const int e  = blockIdx.z >> 1;
    const int kz = blockIdx.z & 1;
    const int n_e = cnt[e];
    const int t0 = blockIdx.y * 128;
    if (t0 >= n_e) return;
    const int nt0 = blockIdx.x * 128;
    const int slot0 = offs[e] + t0;
    const ushort* Be = W2t + (size_t)e * DM * DF;   // [d][k]

    __shared__ char smem[32768];

    const int tid = threadIdx.x;
    const int l = tid & 63, wid = tid >> 6;
    const int wm = (wid >> 1) * 64, wn = (wid & 1) * 64;
    const int lm = l & 15, q = l >> 4;

    f32x4 acc[4][4];
#pragma unroll
    for (int i = 0; i < 4; i++)
#pragma unroll
        for (int j = 0; j < 4; j++) acc[i][j] = (f32x4){0.f, 0.f, 0.f, 0.f};

    const int kbeg = kz * (DF / 2);
    for (int k0 = kbeg; k0 < kbeg + DF / 2; k0 += 64) {
        __syncthreads();
#pragma unroll
        for (int i = 0; i < 4; i++) {
            int cid = i * 256 + tid;
            int row = cid >> 3, p = cid & 7;
            int c = p ^ (row & 7);
            gll16(H + (size_t)(slot0 + row) * DF + k0 + c * 8, smem + cid * 16);
        }
#pragma unroll
        for (int i = 0; i < 4; i++) {
            int cid = i * 256 + tid;
            int n = cid >> 3, p = cid & 7;
            int c = p ^ (n & 7);
            gll16(Be + (size_t)(nt0 + n) * DF + k0 + c * 8, smem + 16384 + cid * 16);
        }
        __syncthreads();
#pragma unroll
        for (int s = 0; s < 2; s++) {
            bf16x8 af[4], bfr[4];
#pragma unroll
            for (int i = 0; i < 4; i++) {
                int row = wm + i * 16 + lm;
                af[i] = *(const bf16x8*)(smem + row * 128 + ((((s << 2) + q) ^ (row & 7)) * 16));
            }
#pragma unroll
            for (int j = 0; j < 4; j++) {
                int n = wn + j * 16 + lm;
                bfr[j] = *(const bf16x8*)(smem + 16384 + n * 128 + ((((s << 2) + q) ^ (n & 7)) * 16));
            }
#pragma unroll
            for (int i = 0; i < 4; i++)
#pragma unroll
                for (int j = 0; j < 4; j++)
                    acc[i][j] = __builtin_amdgcn_mfma_f32_16x16x32_bf16(af[i], bfr[j], acc[i][j], 0, 0, 0);
        }
    }

    float b2v[4];
#pragma unroll
    for (int j = 0; j < 4; j++)
        b2v[j] = (kz == 0) ? b2[e * DM + nt0 + wn + j * 16 + lm] : 0.f;

    float* Ye = Y + (size_t)kz * NSLOT * DM;
#pragma unroll
    for (int i = 0; i < 4; i++)
#pragma unroll
        for (int r = 0; r < 4; r++) {
            int mrow = wm + i * 16 + q * 4 + r;
            if (t0 + mrow < n_e) {   // GUARD: no cross-expert slot writes
                float* yrow = Ye + (size_t)(slot0 + mrow) * DM + nt0;
#pragma unroll
                for (int j = 0; j < 4; j++)
                    yrow[wn + j * 16 + lm] = acc[i][j][r] + b2v[j];
            }
        }
}

// ---------------- combine: out[t] = g0*(Y0+Y1)[s0] + g1*(Y0+Y1)[s1] ----------------
__global__ __launch_bounds__(256)
void combine_kernel(const float* __restrict__ Y, const int* __restrict__ tslot,
                    const float* __restrict__ metaG, float4* __restrict__ out)
{
    const int t = blockIdx.x;          // one token per block (256 threads x float4 = 1024 floats)
    const int c = threadIdx.x;
    int ts = tslot[t];
    int s0 = ts & 0xffff, s1 = (ts >> 16) & 0xffff;
    float g0 = metaG[t], g1 = 1.f - g0;
    const float4* Y0 = (const float4*)Y;
    const float4* Y1 = (const float4*)(Y + (size_t)NSLOT * DM);
    float4 a0 = Y0[(size_t)s0 * (DM / 4) + c];
    float4 a1 = Y1[(size_t)s0 * (DM / 4) + c];
    float4 c0 = Y0[(size_t)s1 * (DM / 4) + c];
    float4 c1 = Y1[(size_t)s1 * (DM / 4) + c];
    float4 o;
    o.x = g0 * (a0.x + a1.x) + g1 * (c0.x + c1.x);
    o.y = g0 * (a0.y + a1.y) + g1 * (c0.y + c1.y);
    o.z = g0 * (a0.z + a1.z) + g1 * (c0.z + c1.z);
    o.w = g0 * (a0.w + a1.w) + g1 * (c0.w + c1.w);
    out[(size_t)t * (DM / 4) + c] = o;
}

extern "C" void kernel_launch(void* const* d_in, const int* in_sizes, int n_in,
                              void* d_out, int out_size, void* d_ws, size_t ws_size,
                              hipStream_t stream)
{
    const float* x  = (const float*)d_in[0];
    const float* Wr = (const float*)d_in[1];
    const float* br = (const float*)d_in[2];
    const float* W1 = (const float*)d_in[3];
    const float* b1 = (const float*)d_in[4];
    const float* W2 = (const float*)d_in[5];
    const float* b2 = (const float*)d_in[6];
    float* out = (float*)d_out;

    char* ws = (char*)d_ws;
    int*    cnt   = (int*)(ws + CNT_OFF);
    int*    offs  = (int*)(ws + OFFS_OFF);
    int*    pos   = (int*)(ws + POS_OFF);
    int*    metaI = (int*)(ws + METAI_OFF);
    float*  metaG = (float*)(ws + METAG_OFF);
    int*    tslot = (int*)(ws + TSLOT_OFF);
    ushort* Xg    = (ushort*)(ws + XG_OFF);
    ushort* W1t   = (ushort*)(ws + W1T_OFF);
    ushort* H     = (ushort*)(ws + H_OFF);
    ushort* W2t   = (ushort*)(ws + W2T_OFF);
    float*  Y     = (float*)(ws + Y_OFF);     // aliases Xg+W1t (both dead after gemm1)

    init_kernel<<<1, 64, 0, stream>>>(cnt);
    wconv_kernel<<<dim3(DF / 64, DM / 64, NE), 256, 0, stream>>>(W1, W1t, DM, DF);
    wconv_kernel<<<dim3(DM / 64, DF / 64, NE), 256, 0, stream>>>(W2, W2t, DF, DM);
    router_kernel<<<TT / 4, 256, 0, stream>>>(x, Wr, br, cnt, metaI, metaG);
    scan_kernel<<<1, 64, 0, stream>>>(cnt, offs, pos);
    scatter_kernel<<<TT / 4, 256, 0, stream>>>(x, metaI, pos, tslot, Xg);

    gemm1_kernel<<<dim3(DF / 128, 32, NE), 256, 0, stream>>>(Xg, W1t, b1, cnt, offs, H);
    gemm2_kernel<<<dim3(DM / 128, 32, NE * 2), 256, 0, stream>>>(H, W2t, b2, cnt, offs, Y);
    combine_kernel<<<TT, 256, 0, stream>>>(Y, tslot, metaG, (float4*)out);
}

// Round 2
// 735.436 us; speedup vs baseline: 1.1247x; 1.0815x over previous
//
#include <hip/hip_runtime.h>

#define TT 4096      // tokens
#define DM 1024      // d_model
#define DF 4096      // d_ff
#define NE 8         // experts
#define NSLOT 8192   // exactly 2*TT slots; tile overreach spills into adjacent ws (masked)

typedef short bf16x8 __attribute__((ext_vector_type(8)));
typedef float f32x4  __attribute__((ext_vector_type(4)));

// ---------- ws layout (bytes), total 218,234,880 (< round-1's 219.5 MB, known OK) ----------
#define CNT_OFF    0
#define OFFS_OFF   256
#define POS_OFF    512
#define METAI_OFF  4096                       // int[TT]
#define METAG_OFF  (METAI_OFF + 4*TT)         // float[TT]
#define TSLOT_OFF  (METAG_OFF + 4*TT)         // int[TT]  (s0 | s1<<16)
#define XG_OFF     131072                     // ushort[NSLOT*DM]   (dead after gemm1)
#define W1T_OFF    (XG_OFF + 2*NSLOT*DM)      // ushort[NE*DF*DM] bf16 [e][f][k] (dead after gemm1)
#define H_OFF      (W1T_OFF + 2*NE*DM*DF)     // ushort[NSLOT*DF]
#define W2T_OFF    (H_OFF + 2*NSLOT*DF)       // ushort[NE*DM*DF] bf16 [e][d][k]
#define Y_OFF      XG_OFF                     // float[2][NSLOT*DM] aliases Xg+W1t (67.1MB <= 83.9MB)

// fp32 pair -> packed bf16x2 (RNE)
__device__ __forceinline__ unsigned pkbf(float a, float b) {
    unsigned ua = __float_as_uint(a), ub = __float_as_uint(b);
    ua += 0x7fffu + ((ua >> 16) & 1u);
    ub += 0x7fffu + ((ub >> 16) & 1u);
    return __builtin_amdgcn_perm(ub, ua, 0x07060302u);
}

// async global->LDS, 16B per lane; LDS dest linear (wave-uniform base + lane*16)
__device__ __forceinline__ void gll16(const void* g, void* l) {
    __builtin_amdgcn_global_load_lds(
        (const __attribute__((address_space(1))) void*)g,
        (__attribute__((address_space(3))) void*)l, 16, 0, 0);
}

// stage one 256x64 A-tile + 256x64 B-tile (bf16) into LDS at dst/dst+32768.
// Linear LDS dest + inverse-XOR-swizzled global source (read key: row&7 / n&7).
__device__ __forceinline__ void stage_tile(const ushort* __restrict__ A, int arow0, int astr,
                                           const ushort* __restrict__ B, int brow0, int bstr,
                                           int k0, char* dst, int tid)
{
#pragma unroll
    for (int i = 0; i < 4; i++) {
        int cid = i * 512 + tid;
        int row = cid >> 3, c = (cid & 7) ^ (row & 7);
        gll16(A + (size_t)(arow0 + row) * astr + k0 + c * 8, dst + cid * 16);
    }
#pragma unroll
    for (int i = 0; i < 4; i++) {
        int cid = i * 512 + tid;
        int n = cid >> 3, c = (cid & 7) ^ (n & 7);
        gll16(B + (size_t)(brow0 + n) * bstr + k0 + c * 8, dst + 32768 + cid * 16);
    }
}

// ---------------- init: zero cnt ----------------
__global__ void init_kernel(int* __restrict__ cnt)
{
    if (threadIdx.x < NE) cnt[threadIdx.x] = 0;
}

// ---------------- Router: 1 wave/token, fp32 exact ----------------
__global__ __launch_bounds__(256)
void router_kernel(const float* __restrict__ x, const float* __restrict__ Wr,
                   const float* __restrict__ br,
                   int* __restrict__ cnt, int* __restrict__ meta_i,
                   float* __restrict__ meta_g)
{
    const int t    = (blockIdx.x * blockDim.x + threadIdx.x) >> 6;
    const int lane = threadIdx.x & 63;
    if (t >= TT) return;
    const float* xr = x + (size_t)t * DM;

    float acc[NE];
#pragma unroll
    for (int e = 0; e < NE; e++) acc[e] = 0.f;
    for (int i = 0; i < DM / 64; i++) {
        int d = lane + (i << 6);
        float xv = xr[d];
        const float4* wr = (const float4*)(Wr + (size_t)d * NE);
        float4 w0 = wr[0], w1 = wr[1];
        acc[0] += xv * w0.x; acc[1] += xv * w0.y;
        acc[2] += xv * w0.z; acc[3] += xv * w0.w;
        acc[4] += xv * w1.x; acc[5] += xv * w1.y;
        acc[6] += xv * w1.z; acc[7] += xv * w1.w;
    }
#pragma unroll
    for (int e = 0; e < NE; e++)
#pragma unroll
        for (int off = 32; off > 0; off >>= 1)
            acc[e] += __shfl_down(acc[e], off, 64);

    if (lane == 0) {
        float lg[NE];
#pragma unroll
        for (int e = 0; e < NE; e++) lg[e] = acc[e] + br[e];
        int i0 = 0;
        for (int e = 1; e < NE; e++) if (lg[e] > lg[i0]) i0 = e;
        int i1 = (i0 == 0) ? 1 : 0;
        for (int e = 0; e < NE; e++) if (e != i0 && lg[e] > lg[i1]) i1 = e;
        float g0 = 1.f / (1.f + expf(lg[i1] - lg[i0]));  // renormalized top-2 softmax
        atomicAdd(&cnt[i0], 1);
        atomicAdd(&cnt[i1], 1);
        meta_i[t] = i0 | (i1 << 8);
        meta_g[t] = g0;
    }
}

// ---------------- scan ----------------
__global__ void scan_kernel(const int* __restrict__ cnt, int* __restrict__ offs,
                            int* __restrict__ pos)
{
    if (threadIdx.x == 0) {
        int o = 0;
        for (int e = 0; e < NE; e++) { offs[e] = o; pos[e] = o; o += cnt[e]; }
    }
}

// ---------------- scatter: slot assign + gather x -> bf16 Xg + token->slot map ----------------
__global__ __launch_bounds__(256)
void scatter_kernel(const float* __restrict__ x, const int* __restrict__ meta_i,
                    int* __restrict__ pos, int* __restrict__ tslot,
                    ushort* __restrict__ Xg)
{
    const int t    = (blockIdx.x * blockDim.x + threadIdx.x) >> 6;
    const int lane = threadIdx.x & 63;
    if (t >= TT) return;
    int s0 = 0, s1 = 0;
    if (lane == 0) {
        int mi = meta_i[t];
        int i0 = mi & 0xff, i1 = (mi >> 8) & 0xff;
        s0 = atomicAdd(&pos[i0], 1);
        s1 = atomicAdd(&pos[i1], 1);
        tslot[t] = s0 | (s1 << 16);
    }
    s0 = __shfl(s0, 0, 64);
    s1 = __shfl(s1, 0, 64);
    const float4* xr = (const float4*)(x + (size_t)t * DM);
#pragma unroll
    for (int i = 0; i < 4; i++) {
        float4 v = xr[lane + 64 * i];
        uint2 pv = make_uint2(pkbf(v.x, v.y), pkbf(v.z, v.w));
        *(uint2*)(Xg + (size_t)s0 * DM + (lane + 64 * i) * 4) = pv;
        *(uint2*)(Xg + (size_t)s1 * DM + (lane + 64 * i) * 4) = pv;
    }
}

// ---------------- wconv: W[e][K][F] fp32 -> Wt[e][F][K] bf16 ----------------
__global__ __launch_bounds__(256)
void wconv_kernel(const float* __restrict__ W, ushort* __restrict__ Wt, int K, int F)
{
    const int e  = blockIdx.z;
    const int k0 = blockIdx.y * 64, f0 = blockIdx.x * 64;
    const float* We = W + (size_t)e * K * F;
    ushort* Oe = Wt + (size_t)e * K * F;

    __shared__ char lds[64 * 136];

    const int tid = threadIdx.x;
    const int a = tid & 15, b = tid >> 4;

    const float* src = We + (size_t)(k0 + b * 4) * F + f0 + a * 4;
    float4 v0 = *(const float4*)(src);
    float4 v1 = *(const float4*)(src + F);
    float4 v2 = *(const float4*)(src + 2 * F);
    float4 v3 = *(const float4*)(src + 3 * F);
    const float* p0 = (const float*)&v0; const float* p1 = (const float*)&v1;
    const float* p2 = (const float*)&v2; const float* p3 = (const float*)&v3;
#pragma unroll
    for (int j = 0; j < 4; j++) {
        int f = a * 4 + j;
        uint2 pv = make_uint2(pkbf(p0[j], p1[j]), pkbf(p2[j], p3[j]));
        *(uint2*)(lds + f * 136 + ((b ^ a) * 8)) = pv;
    }
    __syncthreads();
#pragma unroll
    for (int i = 0; i < 2; i++) {
        int idx = tid + 256 * i;
        int fl = idx >> 3, kc = idx & 7;
        int xw = fl >> 2;
        uint2 lo = *(const uint2*)(lds + fl * 136 + (((kc * 2)     ^ xw) * 8));
        uint2 hi = *(const uint2*)(lds + fl * 136 + (((kc * 2 + 1) ^ xw) * 8));
        uint4 o = make_uint4(lo.x, lo.y, hi.x, hi.y);
        *(uint4*)(Oe + (size_t)(f0 + fl) * K + k0 + kc * 8) = o;
    }
}

// ---------------- GEMM1: H = relu(Xg @ W1t^T + b1), 256^2 tile, 2-phase pipelined ----------------
__global__ __launch_bounds__(512)
void gemm1_kernel(const ushort* __restrict__ Xg, const ushort* __restrict__ W1t,
                  const float* __restrict__ b1, const int* __restrict__ cnt,
                  const int* __restrict__ offs, ushort* __restrict__ H)
{
    const int e = blockIdx.z;
    const int n_e = cnt[e];
    const int t0 = blockIdx.y * 256;
    if (t0 >= n_e) return;
    const int ft0 = blockIdx.x * 256;
    const int slot0 = offs[e] + t0;
    const ushort* Be = W1t + (size_t)e * DF * DM;   // [f][k]

    __shared__ char smem[131072];   // 2 x (A 32K | B 32K); epilogue: Cb 64x264 f32

    const int tid = threadIdx.x;
    const int l = tid & 63, wid = tid >> 6;
    const int wm = (wid >> 2) * 128, wn = (wid & 3) * 64;
    const int lm = l & 15, q = l >> 4;

    f32x4 acc[8][4];
#pragma unroll
    for (int i = 0; i < 8; i++)
#pragma unroll
        for (int j = 0; j < 4; j++) acc[i][j] = (f32x4){0.f, 0.f, 0.f, 0.f};

    // prologue: stage kt=0 into buf0
    stage_tile(Xg, slot0, DM, Be, ft0, DM, 0, smem, tid);
    __syncthreads();

    int cur = 0;
    const int NT = DM / 64;   // 16
    for (int kt = 0; kt < NT; ++kt) {
        // issue next tile's loads FIRST (into the buffer freed at the last barrier);
        // their latency hides under this tile's ds_read+MFMA; the end-of-iter
        // __syncthreads drains vmcnt with the compute already done. (T3-minimal)
        if (kt + 1 < NT)
            stage_tile(Xg, slot0, DM, Be, ft0, DM, (kt + 1) * 64,
                       smem + (cur ^ 1) * 65536, tid);
        const char* Ab = smem + cur * 65536;
        const char* Bb = Ab + 32768;
#pragma unroll
        for (int s = 0; s < 2; s++) {
            bf16x8 af[8], bfr[4];
#pragma unroll
            for (int i = 0; i < 8; i++) {
                int row = wm + i * 16 + lm;
                af[i] = *(const bf16x8*)(Ab + row * 128 + ((((s << 2) + q) ^ (row & 7)) * 16));
            }
#pragma unroll
            for (int j = 0; j < 4; j++) {
                int n = wn + j * 16 + lm;
                bfr[j] = *(const bf16x8*)(Bb + n * 128 + ((((s << 2) + q) ^ (n & 7)) * 16));
            }
#pragma unroll
            for (int i = 0; i < 8; i++)
#pragma unroll
                for (int j = 0; j < 4; j++)
                    acc[i][j] = __builtin_amdgcn_mfma_f32_16x16x32_bf16(af[i], bfr[j], acc[i][j], 0, 0, 0);
        }
        __syncthreads();
        cur ^= 1;
    }

    // epilogue: relu(+b1) -> bf16 H via LDS bounce, 4 stripes of 64 rows
    float b1v[4];
#pragma unroll
    for (int j = 0; j < 4; j++) b1v[j] = b1[e * DF + ft0 + wn + j * 16 + lm];

    float* Cb = (float*)smem;   // [64][264]
#pragma unroll
    for (int s4 = 0; s4 < 4; s4++) {
        if ((wid >> 2) == (s4 >> 1)) {
#pragma unroll
            for (int i = 0; i < 4; i++) {
                int mi = (s4 & 1) * 4 + i;
#pragma unroll
                for (int j = 0; j < 4; j++)
#pragma unroll
                    for (int r = 0; r < 4; r++) {
                        int lr = i * 16 + q * 4 + r;
                        Cb[lr * 264 + wn + j * 16 + lm] = fmaxf(acc[mi][j][r] + b1v[j], 0.f);
                    }
            }
        }
        __syncthreads();
        {
            int row = tid >> 3, seg = tid & 7;
            // GUARD: partial tiles must not write H rows of the next expert's slots
            if (t0 + s4 * 64 + row < n_e) {
                size_t hb = (size_t)(slot0 + s4 * 64 + row) * DF + ft0 + seg * 32;
#pragma unroll
                for (int i = 0; i < 4; i++) {
                    float4 a = *(const float4*)&Cb[row * 264 + seg * 32 + i * 8];
                    float4 b = *(const float4*)&Cb[row * 264 + seg * 32 + i * 8 + 4];
                    uint4 o;
                    o.x = pkbf(a.x, a.y); o.y = pkbf(a.z, a.w);
                    o.z = pkbf(b.x, b.y); o.w = pkbf(b.z, b.w);
                    *(uint4*)(H + hb + i * 8) = o;
                }
            }
        }
        __syncthreads();
    }
}

// ---------------- GEMM2: Y[kz] = H @ W2t^T (+b2 on kz=0), 256^2 tile, 2-phase pipelined ----------------
__global__ __launch_bounds__(512)
void gemm2_kernel(const ushort* __restrict__ H, const ushort* __restrict__ W2t,
                  const float* __restrict__ b2, const int* __restrict__ cnt,
                  const int* __restrict__ offs, float* __restrict__ Y)
{
    const int e  = blockIdx.z >> 1;
    const int kz = blockIdx.z & 1;
    const int n_e = cnt[e];
    const int t0 = blockIdx.y * 256;
    if (t0 >= n_e) return;
    const int nt0 = blockIdx.x * 256;
    const int slot0 = offs[e] + t0;
    const ushort* Be = W2t + (size_t)e * DM * DF;   // [d][k]

    __shared__ char smem[131072];

    const int tid = threadIdx.x;
    const int l = tid & 63, wid = tid >> 6;
    const int wm = (wid >> 2) * 128, wn = (wid & 3) * 64;
    const int lm = l & 15, q = l >> 4;

    f32x4 acc[8][4];
#pragma unroll
    for (int i = 0; i < 8; i++)
#pragma unroll
        for (int j = 0; j < 4; j++) acc[i][j] = (f32x4){0.f, 0.f, 0.f, 0.f};

    const int kbeg = kz * (DF / 2);
    stage_tile(H, slot0, DF, Be, nt0, DF, kbeg, smem, tid);
    __syncthreads();

    int cur = 0;
    const int NT = (DF / 2) / 64;   // 32
    for (int kt = 0; kt < NT; ++kt) {
        if (kt + 1 < NT)
            stage_tile(H, slot0, DF, Be, nt0, DF, kbeg + (kt + 1) * 64,
                       smem + (cur ^ 1) * 65536, tid);
        const char* Ab = smem + cur * 65536;
        const char* Bb = Ab + 32768;
#pragma unroll
        for (int s = 0; s < 2; s++) {
            bf16x8 af[8], bfr[4];
#pragma unroll
            for (int i = 0; i < 8; i++) {
                int row = wm + i * 16 + lm;
                af[i] = *(const bf16x8*)(Ab + row * 128 + ((((s << 2) + q) ^ (row & 7)) * 16));
            }
#pragma unroll
            for (int j = 0; j < 4; j++) {
                int n = wn + j * 16 + lm;
                bfr[j] = *(const bf16x8*)(Bb + n * 128 + ((((s << 2) + q) ^ (n & 7)) * 16));
            }
#pragma unroll
            for (int i = 0; i < 8; i++)
#pragma unroll
                for (int j = 0; j < 4; j++)
                    acc[i][j] = __builtin_amdgcn_mfma_f32_16x16x32_bf16(af[i], bfr[j], acc[i][j], 0, 0, 0);
        }
        __syncthreads();
        cur ^= 1;
    }

    float b2v[4];
#pragma unroll
    for (int j = 0; j < 4; j++)
        b2v[j] = (kz == 0) ? b2[e * DM + nt0 + wn + j * 16 + lm] : 0.f;

    float* Ye = Y + (size_t)kz * NSLOT * DM;
#pragma unroll
    for (int i = 0; i < 8; i++)
#pragma unroll
        for (int r = 0; r < 4; r++) {
            int mrow = wm + i * 16 + q * 4 + r;
            if (t0 + mrow < n_e) {   // GUARD: no cross-expert slot writes
                float* yrow = Ye + (size_t)(slot0 + mrow) * DM + nt0;
#pragma unroll
                for (int j = 0; j < 4; j++)
                    yrow[wn + j * 16 + lm] = acc[i][j][r] + b2v[j];
            }
        }
}

// ---------------- combine: out[t] = g0*(Y0+Y1)[s0] + g1*(Y0+Y1)[s1] ----------------
__global__ __launch_bounds__(256)
void combine_kernel(const float* __restrict__ Y, const int* __restrict__ tslot,
                    const float* __restrict__ metaG, float4* __restrict__ out)
{
    const int t = blockIdx.x;
    const int c = threadIdx.x;
    int ts = tslot[t];
    int s0 = ts & 0xffff, s1 = (ts >> 16) & 0xffff;
    float g0 = metaG[t], g1 = 1.f - g0;
    const float4* Y0 = (const float4*)Y;
    const float4* Y1 = (const float4*)(Y + (size_t)NSLOT * DM);
    float4 a0 = Y0[(size_t)s0 * (DM / 4) + c];
    float4 a1 = Y1[(size_t)s0 * (DM / 4) + c];
    float4 c0 = Y0[(size_t)s1 * (DM / 4) + c];
    float4 c1 = Y1[(size_t)s1 * (DM / 4) + c];
    float4 o;
    o.x = g0 * (a0.x + a1.x) + g1 * (c0.x + c1.x);
    o.y = g0 * (a0.y + a1.y) + g1 * (c0.y + c1.y);
    o.z = g0 * (a0.z + a1.z) + g1 * (c0.z + c1.z);
    o.w = g0 * (a0.w + a1.w) + g1 * (c0.w + c1.w);
    out[(size_t)t * (DM / 4) + c] = o;
}

extern "C" void kernel_launch(void* const* d_in, const int* in_sizes, int n_in,
                              void* d_out, int out_size, void* d_ws, size_t ws_size,
                              hipStream_t stream)
{
    const float* x  = (const float*)d_in[0];
    const float* Wr = (const float*)d_in[1];
    const float* br = (const float*)d_in[2];
    const float* W1 = (const float*)d_in[3];
    const float* b1 = (const float*)d_in[4];
    const float* W2 = (const float*)d_in[5];
    const float* b2 = (const float*)d_in[6];
    float* out = (float*)d_out;

    char* ws = (char*)d_ws;
    int*    cnt   = (int*)(ws + CNT_OFF);
    int*    offs  = (int*)(ws + OFFS_OFF);
    int*    pos   = (int*)(ws + POS_OFF);
    int*    metaI = (int*)(ws + METAI_OFF);
    float*  metaG = (float*)(ws + METAG_OFF);
    int*    tslot = (int*)(ws + TSLOT_OFF);
    ushort* Xg    = (ushort*)(ws + XG_OFF);
    ushort* W1t   = (ushort*)(ws + W1T_OFF);
    ushort* H     = (ushort*)(ws + H_OFF);
    ushort* W2t   = (ushort*)(ws + W2T_OFF);
    float*  Y     = (float*)(ws + Y_OFF);     // aliases Xg+W1t (both dead after gemm1)

    init_kernel<<<1, 64, 0, stream>>>(cnt);
    wconv_kernel<<<dim3(DF / 64, DM / 64, NE), 256, 0, stream>>>(W1, W1t, DM, DF);
    wconv_kernel<<<dim3(DM / 64, DF / 64, NE), 256, 0, stream>>>(W2, W2t, DF, DM);
    router_kernel<<<TT / 4, 256, 0, stream>>>(x, Wr, br, cnt, metaI, metaG);
    scan_kernel<<<1, 64, 0, stream>>>(cnt, offs, pos);
    scatter_kernel<<<TT / 4, 256, 0, stream>>>(x, metaI, pos, tslot, Xg);

    gemm1_kernel<<<dim3(DF / 256, 16, NE), 512, 0, stream>>>(Xg, W1t, b1, cnt, offs, H);
    gemm2_kernel<<<dim3(DM / 256, 16, NE * 2), 512, 0, stream>>>(H, W2t, b2, cnt, offs, Y);
    combine_kernel<<<TT, 256, 0, stream>>>(Y, tslot, metaG, (float4*)out);
}